// Round 11
// baseline (276.473 us; speedup 1.0000x reference)
//
#include <hip/hip_runtime.h>
#include <hip/hip_bf16.h>
#include <stdint.h>

typedef __attribute__((ext_vector_type(4))) float f32x4;
typedef __attribute__((ext_vector_type(8))) short short8;
typedef __attribute__((ext_vector_type(4))) int int4v;

#define IN_F   8192
#define OUT_F  8192
#define MROWS  256
#define NGRP   128
#define QROW   4096
#define NSLICE 4
#define KT_PER 32    // 4*32*64 = 8192 = full K

__device__ unsigned short g_xb[MROWS * IN_F];             // 4 MB bf16 x, fragment-major
__device__ float          g_t[MROWS * 16];
__device__ float          g_part[NSLICE * MROWS * OUT_F]; // 32 MB split-K partials
__device__ float          g_dbg[1024 * 256];              // ablation sink

__device__ __constant__ float NF4_LVL[16] = {
  -1.0f,        -0.70756721f, -0.54221982f, -0.41681853f,
  -0.31090474f, -0.21594601f, -0.12734085f, -0.04209530f,
   0.04209530f,  0.12734085f,  0.21594601f,  0.31090474f,
   0.41681853f,  0.54221982f,  0.70756721f,  1.0f };

static __device__ inline uint32_t pkbf(float a, float b) {
  __bf16 ha = (__bf16)a, hb = (__bf16)b;
  return (uint32_t)__builtin_bit_cast(unsigned short, ha)
       | ((uint32_t)__builtin_bit_cast(unsigned short, hb) << 16);
}

__global__ __launch_bounds__(256) void k_convert(const float* __restrict__ x) {
  int d = blockIdx.x * 256 + threadIdx.x;
  int l15 = d & 15, sub = (d >> 4) & 3, kk = (d >> 6) & 1;
  int m16 = (d >> 7) & 15, kt = d >> 11;
  int r = m16 * 16 + l15;
  int k = kt * 64 + (kk * 4 + sub) * 8;
  const float* src = x + (size_t)r * IN_F + k;
  f32x4 v0 = *(const f32x4*)src;
  f32x4 v1 = *(const f32x4*)(src + 4);
  int4v ov;
  ov[0] = (int)pkbf(v0.x, v0.y); ov[1] = (int)pkbf(v0.z, v0.w);
  ov[2] = (int)pkbf(v1.x, v1.y); ov[3] = (int)pkbf(v1.z, v1.w);
  *(int4v*)(g_xb + (size_t)d * 8) = ov;
}

__global__ __launch_bounds__(256) void k_xa(const float* __restrict__ x,
                                            const float* __restrict__ lora_A) {
  int m = blockIdx.x, tid = threadIdx.x;
  float acc[16];
#pragma unroll
  for (int r = 0; r < 16; ++r) acc[r] = 0.f;
  const float* xr = x + (size_t)m * IN_F;
  for (int it = 0; it < 8; ++it) {
    int k = (tid + it * 256) * 4;
    f32x4 xv = *(const f32x4*)(xr + k);
#pragma unroll
    for (int r = 0; r < 16; ++r) {
      f32x4 av = *(const f32x4*)(lora_A + (size_t)r * IN_F + k);
      acc[r] += xv.x * av.x + xv.y * av.y + xv.z * av.z + xv.w * av.w;
    }
  }
#pragma unroll
  for (int r = 0; r < 16; ++r) {
    float v = acc[r];
#pragma unroll
    for (int off = 32; off; off >>= 1) v += __shfl_xor(v, off, 64);
    acc[r] = v;
  }
  __shared__ float sm[4][16];
  int lane = tid & 63, wave = tid >> 6;
  if (lane == 0) {
#pragma unroll
    for (int r = 0; r < 16; ++r) sm[wave][r] = acc[r];
  }
  __syncthreads();
  if (tid < 16)
    g_t[m * 16 + tid] = 2.0f * (sm[0][tid] + sm[1][tid] + sm[2][tid] + sm[3][tid]);
}

// Ablation: V0=full  V1=no-A  V2=no-B(dequant)  V3=MFMA-only  V4=no-MFMA
template<int V>
__global__ __launch_bounds__(256, 4) void k_gemm(
    const int* __restrict__ qw, const float* __restrict__ scales)
{
  constexpr bool USE_A = (V != 1 && V != 3);
  constexpr bool USE_B = (V != 2 && V != 3);
  constexpr bool USE_M = (V != 4);

  __shared__ unsigned short Bl[2][64 * 64];
  __shared__ uint32_t lut2[256];

  int tid = threadIdx.x;
  int lane = tid & 63, wave = tid >> 6;
  if (USE_B) lut2[tid] = pkbf(NF4_LVL[tid >> 4], NF4_LVL[tid & 15]);

  int flat = blockIdx.x;
  int wg = (flat & 7) * 128 + (flat >> 3);
  int bx = wg & 127;
  int mt = (wg >> 7) & 1;
  int bz = wg >> 8;
  int n0 = bx * 64;
  int m0 = mt * 128;
  int ktg0 = bz * KT_PER;

  int wr = wave >> 1, wc = wave & 1;
  int sub = lane >> 4, l15 = lane & 15;

  int r0 = tid >> 3, c0 = tid & 7;
  int r1 = (tid + 256) >> 3;
  const int* qp0 = qw + (size_t)(n0 + r0) * QROW + c0 * 4;
  const int* qp1 = qw + (size_t)(n0 + r1) * QROW + c0 * 4;
  int boff0 = r0 * 128 + ((c0 ^ (r0 & 7)) << 4);
  int boff1 = r1 * 128 + ((c0 ^ (r1 & 7)) << 4);

  const float* sp0 = scales + (size_t)(n0 + wc * 32 + l15) * NGRP;
  const float* sp1 = sp0 + 16 * NGRP;

  const unsigned short* abase =
      g_xb + (size_t)(mt * 8 + wr * 4) * 1024 + (sub * 16 + l15) * 8;

  f32x4 acc[4][2];
#pragma unroll
  for (int i = 0; i < 4; ++i)
#pragma unroll
    for (int j = 0; j < 2; ++j) acc[i][j] = (f32x4){0.f, 0.f, 0.f, 0.f};

  auto dqst = [&](int buf, int4v q0, int4v q1) {
    int4v ov;
#pragma unroll
    for (int e = 0; e < 4; ++e) ov[e] = (int)lut2[q0[e] & 255];
    *(int4v*)((char*)(&Bl[buf][0]) + boff0) = ov;
#pragma unroll
    for (int e = 0; e < 4; ++e) ov[e] = (int)lut2[q1[e] & 255];
    *(int4v*)((char*)(&Bl[buf][0]) + boff1) = ov;
  };

  // constant fragments for ablated paths (kept live via asm)
  short8 cfrag;
#pragma unroll
  for (int e = 0; e < 8; ++e) cfrag[e] = (short)(lane + e);
  asm volatile("" : "+v"(cfrag));

  int4v qn0, qn1;
  float sc0 = 1.f, sc1 = 1.f, sx0 = 1.f, sx1 = 1.f;

  if (USE_B) {
    __syncthreads();  // lut ready
    size_t ko = (size_t)ktg0 * 32;
    int4v qa0 = *(const int4v*)(qp0 + ko);
    int4v qa1 = *(const int4v*)(qp1 + ko);
    dqst(0, qa0, qa1);
    qn0 = *(const int4v*)(qp0 + (size_t)(ktg0 + 1) * 32);
    qn1 = *(const int4v*)(qp1 + (size_t)(ktg0 + 1) * 32);
    sc0 = sp0[ktg0];     sc1 = sp1[ktg0];
    sx0 = sp0[ktg0 + 1]; sx1 = sp1[ktg0 + 1];
    asm volatile("s_waitcnt lgkmcnt(0)" ::: "memory");
    __builtin_amdgcn_s_barrier();
  }

  for (int t = 0; t < KT_PER; ++t) {
    int cur = t & 1;
    int ktg = ktg0 + t;

    short8 af[2][4];
    if (USE_A) {
      const unsigned short* ab = abase + (size_t)ktg * 16384;
#pragma unroll
      for (int kk = 0; kk < 2; ++kk)
#pragma unroll
        for (int mi = 0; mi < 4; ++mi)
          af[kk][mi] = *(const short8*)(ab + mi * 1024 + kk * 512);
    } else {
#pragma unroll
      for (int kk = 0; kk < 2; ++kk)
#pragma unroll
        for (int mi = 0; mi < 4; ++mi) af[kk][mi] = cfrag;
    }

    if (USE_B) {
      int4v qf0, qf1;
      float sf0 = 0.f, sf1 = 0.f;
      if (t < KT_PER - 2) {
        size_t ko = (size_t)(ktg + 2) * 32;
        qf0 = *(const int4v*)(qp0 + ko);
        qf1 = *(const int4v*)(qp1 + ko);
        sf0 = sp0[ktg + 2]; sf1 = sp1[ktg + 2];
      }
      if (t < KT_PER - 1) dqst(cur ^ 1, qn0, qn1);
      qn0 = qf0; qn1 = qf1;

#pragma unroll
      for (int ni = 0; ni < 2; ++ni) {
        short8 bfv[2];
#pragma unroll
        for (int kk = 0; kk < 2; ++kk) {
          int n = wc * 32 + ni * 16 + l15;
          int cch = (kk * 4 + sub) ^ (n & 7);
          bfv[kk] = *(const short8*)((const char*)(&Bl[cur][0]) + n * 128 + cch * 16);
        }
        if (USE_M) {
          f32x4 tacc[4];
#pragma unroll
          for (int mi = 0; mi < 4; ++mi) tacc[mi] = (f32x4){0.f, 0.f, 0.f, 0.f};
          __builtin_amdgcn_s_setprio(1);
#pragma unroll
          for (int kk = 0; kk < 2; ++kk)
#pragma unroll
            for (int mi = 0; mi < 4; ++mi)
              tacc[mi] = __builtin_amdgcn_mfma_f32_16x16x32_bf16(
                  af[kk][mi], bfv[kk], tacc[mi], 0, 0, 0);
          __builtin_amdgcn_s_setprio(0);
          float s = ni ? sc1 : sc0;
#pragma unroll
          for (int mi = 0; mi < 4; ++mi) {
            acc[mi][ni].x += s * tacc[mi].x;
            acc[mi][ni].y += s * tacc[mi].y;
            acc[mi][ni].z += s * tacc[mi].z;
            acc[mi][ni].w += s * tacc[mi].w;
          }
        } else {
          // V4: keep loads live with cheap VALU
#pragma unroll
          for (int kk = 0; kk < 2; ++kk) {
            acc[0][ni].x += (float)bfv[kk][0];
#pragma unroll
            for (int mi = 0; mi < 4; ++mi)
              acc[mi][ni].y += (float)af[kk][mi][0];
          }
        }
      }
      sc0 = sx0; sc1 = sx1;
      sx0 = (t < KT_PER - 2) ? sp0[ktg + 2] : 1.f;   // loaded above; cheap re-read folded
      sx1 = (t < KT_PER - 2) ? sp1[ktg + 2] : 1.f;

      if (t < KT_PER - 1) {
        asm volatile("s_waitcnt lgkmcnt(0)" ::: "memory");
        __builtin_amdgcn_s_barrier();
      }
    } else {
      // no-B variants: constant B fragment
#pragma unroll
      for (int ni = 0; ni < 2; ++ni) {
        if (USE_M) {
          f32x4 tacc[4];
#pragma unroll
          for (int mi = 0; mi < 4; ++mi) tacc[mi] = (f32x4){0.f, 0.f, 0.f, 0.f};
          __builtin_amdgcn_s_setprio(1);
#pragma unroll
          for (int kk = 0; kk < 2; ++kk)
#pragma unroll
            for (int mi = 0; mi < 4; ++mi)
              tacc[mi] = __builtin_amdgcn_mfma_f32_16x16x32_bf16(
                  af[kk][mi], cfrag, tacc[mi], 0, 0, 0);
          __builtin_amdgcn_s_setprio(0);
#pragma unroll
          for (int mi = 0; mi < 4; ++mi) {
            acc[mi][ni].x += tacc[mi].x; acc[mi][ni].y += tacc[mi].y;
            acc[mi][ni].z += tacc[mi].z; acc[mi][ni].w += tacc[mi].w;
          }
        } else {
#pragma unroll
          for (int kk = 0; kk < 2; ++kk)
#pragma unroll
            for (int mi = 0; mi < 4; ++mi)
              acc[mi][ni].y += (float)af[kk][mi][0];
        }
      }
    }
  }

  if (V == 0) {
    float* op = g_part + (size_t)bz * MROWS * OUT_F;
#pragma unroll
    for (int mi = 0; mi < 4; ++mi) {
#pragma unroll
      for (int ni = 0; ni < 2; ++ni) {
        int m = m0 + wr * 64 + mi * 16 + sub * 4;
        int nn = n0 + wc * 32 + ni * 16 + l15;
#pragma unroll
        for (int j = 0; j < 4; ++j)
          op[(size_t)(m + j) * OUT_F + nn] = acc[mi][ni][j];
      }
    }
  } else {
    float sink = 0.f;
#pragma unroll
    for (int mi = 0; mi < 4; ++mi)
#pragma unroll
      for (int ni = 0; ni < 2; ++ni)
        sink += acc[mi][ni].x + acc[mi][ni].y + acc[mi][ni].z + acc[mi][ni].w;
    g_dbg[(size_t)blockIdx.x * 256 + tid] = sink;
  }
}

__global__ __launch_bounds__(256) void k_reduce(const float* __restrict__ lora_B,
                                                float* __restrict__ out) {
  size_t i = ((size_t)blockIdx.x * 256 + threadIdx.x) * 4;
  int m = (int)(i >> 13);
  int n = (int)(i & 8191);
  f32x4 v = *(const f32x4*)(g_part + i);
#pragma unroll
  for (int s = 1; s < NSLICE; ++s)
    v += *(const f32x4*)(g_part + (size_t)s * MROWS * OUT_F + i);
  const float* tr = g_t + m * 16;
  f32x4 t0 = *(const f32x4*)tr,       t1 = *(const f32x4*)(tr + 4);
  f32x4 t2 = *(const f32x4*)(tr + 8), t3 = *(const f32x4*)(tr + 12);
#pragma unroll
  for (int j = 0; j < 4; ++j) {
    const float* br = lora_B + (size_t)(n + j) * 16;
    f32x4 b0 = *(const f32x4*)br,       b1 = *(const f32x4*)(br + 4);
    f32x4 b2 = *(const f32x4*)(br + 8), b3 = *(const f32x4*)(br + 12);
    v[j] += t0.x*b0.x + t0.y*b0.y + t0.z*b0.z + t0.w*b0.w
          + t1.x*b1.x + t1.y*b1.y + t1.z*b1.z + t1.w*b1.w
          + t2.x*b2.x + t2.y*b2.y + t2.z*b2.z + t2.w*b2.w
          + t3.x*b3.x + t3.y*b3.y + t3.z*b3.z + t3.w*b3.w;
  }
  *(f32x4*)(out + i) = v;
}

extern "C" void kernel_launch(void* const* d_in, const int* in_sizes, int n_in,
                              void* d_out, int out_size, void* d_ws, size_t ws_size,
                              hipStream_t stream) {
  const float* x  = (const float*)d_in[0];
  const int*   qw = (const int*)d_in[1];
  const float* sc = (const float*)d_in[2];
  const float* lA = (const float*)d_in[3];
  const float* lB = (const float*)d_in[4];
  float* out = (float*)d_out;

  k_convert<<<1024, 256, 0, stream>>>(x);
  k_xa<<<256, 256, 0, stream>>>(x, lA);
  // ablation probes (results -> g_dbg; timings via rocprof per-dispatch rows)
  k_gemm<3><<<1024, 256, 0, stream>>>(qw, sc);  // MFMA-only scaffold
  k_gemm<2><<<1024, 256, 0, stream>>>(qw, sc);  // A + MFMA
  k_gemm<1><<<1024, 256, 0, stream>>>(qw, sc);  // B(dequant) + MFMA
  k_gemm<4><<<1024, 256, 0, stream>>>(qw, sc);  // loads only, no MFMA
  // real kernel
  k_gemm<0><<<1024, 256, 0, stream>>>(qw, sc);
  k_reduce<<<2048, 256, 0, stream>>>(lB, out);
}

// Round 12
// 158.432 us; speedup vs baseline: 1.7451x; 1.7451x over previous
//
#include <hip/hip_runtime.h>
#include <hip/hip_bf16.h>
#include <stdint.h>

typedef __attribute__((ext_vector_type(4))) float f32x4;
typedef __attribute__((ext_vector_type(8))) short short8;
typedef __attribute__((ext_vector_type(4))) int int4v;

#define IN_F   8192
#define OUT_F  8192
#define MROWS  256
#define NGRP   128
#define QROW   4096  // int32s per q_weight row (each int32 holds ONE packed byte)
#define NSLICE 4
#define KT_PER 32    // 4*32*64 = 8192 = full K

__device__ unsigned short g_xb[MROWS * IN_F];             // 4 MB bf16 x, fragment-major (k-permuted)
__device__ float          g_t[MROWS * 16];
__device__ float          g_part[NSLICE * MROWS * OUT_F]; // 32 MB split-K partials

static __device__ inline uint32_t pkbf(float a, float b) {
  __bf16 ha = (__bf16)a, hb = (__bf16)b;
  return (uint32_t)__builtin_bit_cast(unsigned short, ha)
       | ((uint32_t)__builtin_bit_cast(unsigned short, hb) << 16);
}

// ---- k0: x fp32 -> bf16, fragment-major, k-permuted [0,2,4,6,1,3,5,7] within each 8
__global__ __launch_bounds__(256) void k_convert(const float* __restrict__ x) {
  int d = blockIdx.x * 256 + threadIdx.x;   // 262144 chunks of 8 bf16
  int l15 = d & 15, sub = (d >> 4) & 3, kk = (d >> 6) & 1;
  int m16 = (d >> 7) & 15, kt = d >> 11;
  int r = m16 * 16 + l15;
  int k = kt * 64 + (kk * 4 + sub) * 8;
  const float* src = x + (size_t)r * IN_F + k;
  f32x4 v0 = *(const f32x4*)src;        // k+0..3
  f32x4 v1 = *(const f32x4*)(src + 4);  // k+4..7
  int4v ov;
  ov[0] = (int)pkbf(v0.x, v0.z);  // slots 0,1 = k0,k2
  ov[1] = (int)pkbf(v1.x, v1.z);  // slots 2,3 = k4,k6
  ov[2] = (int)pkbf(v0.y, v0.w);  // slots 4,5 = k1,k3
  ov[3] = (int)pkbf(v1.y, v1.w);  // slots 6,7 = k5,k7
  *(int4v*)(g_xb + (size_t)d * 8) = ov;
}

// ---- k1: g_t = 2 * x @ lora_A^T
__global__ __launch_bounds__(256) void k_xa(const float* __restrict__ x,
                                            const float* __restrict__ lora_A) {
  int m = blockIdx.x, tid = threadIdx.x;
  float acc[16];
#pragma unroll
  for (int r = 0; r < 16; ++r) acc[r] = 0.f;
  const float* xr = x + (size_t)m * IN_F;
  for (int it = 0; it < 8; ++it) {
    int k = (tid + it * 256) * 4;
    f32x4 xv = *(const f32x4*)(xr + k);
#pragma unroll
    for (int r = 0; r < 16; ++r) {
      f32x4 av = *(const f32x4*)(lora_A + (size_t)r * IN_F + k);
      acc[r] += xv.x * av.x + xv.y * av.y + xv.z * av.z + xv.w * av.w;
    }
  }
#pragma unroll
  for (int r = 0; r < 16; ++r) {
    float v = acc[r];
#pragma unroll
    for (int off = 32; off; off >>= 1) v += __shfl_xor(v, off, 64);
    acc[r] = v;
  }
  __shared__ float sm[4][16];
  int lane = tid & 63, wave = tid >> 6;
  if (lane == 0) {
#pragma unroll
    for (int r = 0; r < 16; ++r) sm[wave][r] = acc[r];
  }
  __syncthreads();
  if (tid < 16)
    g_t[m * 16 + tid] = 2.0f * (sm[0][tid] + sm[1][tid] + sm[2][tid] + sm[3][tid]);
}

// VALU NF4 dequant: 4 q-ints (4 bytes = 8 weights) -> bf16 short8 in permuted k-order.
// NF4 symmetry: lv[n] = sign(n<8) * mag[(n ^ (n<8?7:0)) & 7].
static __device__ inline int4v dq8(int4v q,
                                   uint32_t hiT1, uint32_t hiT0,
                                   uint32_t loT1, uint32_t loT0) {
  uint32_t q0 = (uint32_t)q[0], q1 = (uint32_t)q[1];
  uint32_t q2 = (uint32_t)q[2], q3 = (uint32_t)q[3];
  // compact the 4 low bytes into one dword [b0,b1,b2,b3]
  uint32_t p01 = __builtin_amdgcn_perm(q1, q0, 0x00000400u);
  uint32_t p23 = __builtin_amdgcn_perm(q3, q2, 0x00000400u);
  uint32_t pk4 = __builtin_amdgcn_perm(p23, p01, 0x05040100u);

  uint32_t nh = (pk4 >> 4) & 0x0F0F0F0Fu;   // hi nibbles -> even k
  uint32_t nl = pk4 & 0x0F0F0F0Fu;          // lo nibbles -> odd k

  uint32_t nb3H = (~nh) & 0x08080808u;
  uint32_t m7H  = nb3H - (nb3H >> 3);
  uint32_t mgH  = (nh ^ m7H) & 0x07070707u;
  uint32_t sgH  = nb3H << 4;
  uint32_t hibH = __builtin_amdgcn_perm(hiT1, hiT0, mgH) | sgH;
  uint32_t lobH = __builtin_amdgcn_perm(loT1, loT0, mgH);

  uint32_t nb3L = (~nl) & 0x08080808u;
  uint32_t m7L  = nb3L - (nb3L >> 3);
  uint32_t mgL  = (nl ^ m7L) & 0x07070707u;
  uint32_t sgL  = nb3L << 4;
  uint32_t hibL = __builtin_amdgcn_perm(hiT1, hiT0, mgL) | sgL;
  uint32_t lobL = __builtin_amdgcn_perm(loT1, loT0, mgL);

  int4v r;
  r[0] = (int)__builtin_amdgcn_perm(hibH, lobH, 0x05010400u);  // (w_k0, w_k2)
  r[1] = (int)__builtin_amdgcn_perm(hibH, lobH, 0x07030602u);  // (w_k4, w_k6)
  r[2] = (int)__builtin_amdgcn_perm(hibL, lobL, 0x05010400u);  // (w_k1, w_k3)
  r[3] = (int)__builtin_amdgcn_perm(hibL, lobL, 0x07030602u);  // (w_k5, w_k7)
  return r;
}

// ---- k3: main GEMM. 256 blocks (1/CU) x 512 thr = 8 waves (4 M-groups x 2 N-halves),
// per-wave M64 x N64, BN=128, split-K=4. ZERO LDS, ZERO barriers: B dequanted in
// registers via v_perm bit-slicing; scale folded post-MFMA in fp32; A from L2.
__global__ __launch_bounds__(512, 2) void k_gemm(
    const int* __restrict__ qw, const float* __restrict__ scales)
{
  int tid = threadIdx.x;
  int lane = tid & 63, wave = tid >> 6;

  // magnitude byte-tables (compile-time folded)
  const float mags[8] = {0.04209530f, 0.12734085f, 0.21594601f, 0.31090474f,
                         0.41681853f, 0.54221982f, 0.70756721f, 1.0f};
  uint32_t loT0 = 0, loT1 = 0, hiT0 = 0, hiT1 = 0;
#pragma unroll
  for (int i = 0; i < 4; ++i) {
    uint32_t b = pkbf(mags[i], 0.f) & 0xFFFFu;
    loT0 |= (b & 0xFFu) << (8 * i); hiT0 |= (b >> 8) << (8 * i);
  }
#pragma unroll
  for (int i = 0; i < 4; ++i) {
    uint32_t b = pkbf(mags[4 + i], 0.f) & 0xFFFFu;
    loT1 |= (b & 0xFFu) << (8 * i); hiT1 |= (b >> 8) << (8 * i);
  }

  // XCD-aware swizzle over 256 blocks
  int flat = blockIdx.x;
  int wg = (flat & 7) * 32 + (flat >> 3);
  int bx = wg & 63, bz = wg >> 6;
  int n0 = bx * 128;
  int ktg0 = bz * KT_PER;

  int wr = wave >> 1, wc = wave & 1;   // 4 M-groups x 2 N-halves
  int sub = lane >> 4, l15 = lane & 15;

  const int* qp[4];
  const float* sp[4];
#pragma unroll
  for (int ni = 0; ni < 4; ++ni) {
    size_t rowb = (size_t)(n0 + wc * 64 + ni * 16 + l15);
    qp[ni] = qw + rowb * QROW + (size_t)sub * 4;
    sp[ni] = scales + rowb * NGRP;
  }
  const unsigned short* abase =
      g_xb + (size_t)(wr * 4) * 1024 + (sub * 16 + l15) * 8;

  f32x4 acc[4][4];   // [mi][ni]
#pragma unroll
  for (int i = 0; i < 4; ++i)
#pragma unroll
    for (int j = 0; j < 4; ++j) acc[i][j] = (f32x4){0.f, 0.f, 0.f, 0.f};

  // prefetch tile 0 q/scales
  int4v qb[8]; float sb[4];
#pragma unroll
  for (int ni = 0; ni < 4; ++ni) {
#pragma unroll
    for (int kk = 0; kk < 2; ++kk)
      qb[ni * 2 + kk] = *(const int4v*)(qp[ni] + (size_t)ktg0 * 32 + kk * 16);
    sb[ni] = sp[ni][ktg0];
  }

#pragma clang loop unroll(disable)
  for (int t = 0; t < KT_PER; ++t) {
    int ktg = ktg0 + t;

    // A frags for this tile (8 x b128 from L2)
    short8 af[2][4];
    const unsigned short* ab = abase + (size_t)ktg * 16384;
#pragma unroll
    for (int kk = 0; kk < 2; ++kk)
#pragma unroll
      for (int mi = 0; mi < 4; ++mi)
        af[kk][mi] = *(const short8*)(ab + mi * 1024 + kk * 512);

    // prefetch q/scales for t+1 (in flight under dequant+MFMA)
    int tn = (t < KT_PER - 1) ? (t + 1) : t;
    int4v qn[8]; float sn[4];
#pragma unroll
    for (int ni = 0; ni < 4; ++ni) {
#pragma unroll
      for (int kk = 0; kk < 2; ++kk)
        qn[ni * 2 + kk] = *(const int4v*)(qp[ni] + (size_t)(ktg0 + tn) * 32 + kk * 16);
      sn[ni] = sp[ni][ktg0 + tn];
    }

    // dequant current q -> bf16 B frags (pure VALU, no LDS)
    int4v bq[8];
#pragma unroll
    for (int u = 0; u < 8; ++u)
      bq[u] = dq8(qb[u], hiT1, hiT0, loT1, loT0);

    // MFMA per ni into tacc, then fold scale in fp32
#pragma unroll
    for (int ni = 0; ni < 4; ++ni) {
      f32x4 tacc[4];
#pragma unroll
      for (int mi = 0; mi < 4; ++mi) tacc[mi] = (f32x4){0.f, 0.f, 0.f, 0.f};
      __builtin_amdgcn_s_setprio(1);
#pragma unroll
      for (int kk = 0; kk < 2; ++kk) {
        short8 bs = __builtin_bit_cast(short8, bq[ni * 2 + kk]);
#pragma unroll
        for (int mi = 0; mi < 4; ++mi)
          tacc[mi] = __builtin_amdgcn_mfma_f32_16x16x32_bf16(
              af[kk][mi], bs, tacc[mi], 0, 0, 0);
      }
      __builtin_amdgcn_s_setprio(0);
      float s = sb[ni];
#pragma unroll
      for (int mi = 0; mi < 4; ++mi) {
        acc[mi][ni].x += s * tacc[mi].x;
        acc[mi][ni].y += s * tacc[mi].y;
        acc[mi][ni].z += s * tacc[mi].z;
        acc[mi][ni].w += s * tacc[mi].w;
      }
    }

#pragma unroll
    for (int i = 0; i < 8; ++i) qb[i] = qn[i];
#pragma unroll
    for (int i = 0; i < 4; ++i) sb[i] = sn[i];
  }

  // epilogue -> per-slice partials. D layout: col=lane&15, row=(lane>>4)*4+reg
  float* op = g_part + (size_t)bz * MROWS * OUT_F;
#pragma unroll
  for (int mi = 0; mi < 4; ++mi) {
#pragma unroll
    for (int ni = 0; ni < 4; ++ni) {
      int m = wr * 64 + mi * 16 + sub * 4;
      int nn = n0 + wc * 64 + ni * 16 + l15;
#pragma unroll
      for (int j = 0; j < 4; ++j)
        op[(size_t)(m + j) * OUT_F + nn] = acc[mi][ni][j];
    }
  }
}

// ---- k4: out = sum of 4 split-K partials + LoRA (g_t @ lora_B^T), fused
__global__ __launch_bounds__(256) void k_reduce(const float* __restrict__ lora_B,
                                                float* __restrict__ out) {
  size_t i = ((size_t)blockIdx.x * 256 + threadIdx.x) * 4;
  int m = (int)(i >> 13);
  int n = (int)(i & 8191);
  f32x4 v = *(const f32x4*)(g_part + i);
#pragma unroll
  for (int s = 1; s < NSLICE; ++s)
    v += *(const f32x4*)(g_part + (size_t)s * MROWS * OUT_F + i);
  const float* tr = g_t + m * 16;
  f32x4 t0 = *(const f32x4*)tr,       t1 = *(const f32x4*)(tr + 4);
  f32x4 t2 = *(const f32x4*)(tr + 8), t3 = *(const f32x4*)(tr + 12);
#pragma unroll
  for (int j = 0; j < 4; ++j) {
    const float* br = lora_B + (size_t)(n + j) * 16;
    f32x4 b0 = *(const f32x4*)br,       b1 = *(const f32x4*)(br + 4);
    f32x4 b2 = *(const f32x4*)(br + 8), b3 = *(const f32x4*)(br + 12);
    v[j] += t0.x*b0.x + t0.y*b0.y + t0.z*b0.z + t0.w*b0.w
          + t1.x*b1.x + t1.y*b1.y + t1.z*b1.z + t1.w*b1.w
          + t2.x*b2.x + t2.y*b2.y + t2.z*b2.z + t2.w*b2.w
          + t3.x*b3.x + t3.y*b3.y + t3.z*b3.z + t3.w*b3.w;
  }
  *(f32x4*)(out + i) = v;
}

extern "C" void kernel_launch(void* const* d_in, const int* in_sizes, int n_in,
                              void* d_out, int out_size, void* d_ws, size_t ws_size,
                              hipStream_t stream) {
  const float* x  = (const float*)d_in[0];
  const int*   qw = (const int*)d_in[1];
  const float* sc = (const float*)d_in[2];
  const float* lA = (const float*)d_in[3];
  const float* lB = (const float*)d_in[4];
  float* out = (float*)d_out;

  k_convert<<<1024, 256, 0, stream>>>(x);
  k_xa<<<256, 256, 0, stream>>>(x, lA);
  k_gemm<<<256, 512, 0, stream>>>(qw, sc);
  k_reduce<<<2048, 256, 0, stream>>>(lB, out);
}